// Round 1
// baseline (168.228 us; speedup 1.0000x reference)
//
#include <hip/hip_runtime.h>
#include <hip/hip_bf16.h>

typedef __attribute__((ext_vector_type(4))) float floatx4;

#define C_DIM 256
#define INV_T 14.285714285714286f
// (1/T) * log2(e) : logits scaled to base-2 so exp2f -> v_exp_f32 directly.
#define K2_SCALE 20.60992915f

// pack 4 fp32 -> 4 OCP fp8 e4m3 bytes in one dword (ascending order)
__device__ __forceinline__ unsigned int pack4fp8(float a, float b, float c, float d) {
    int w = __builtin_amdgcn_cvt_pk_fp8_f32(a, b, 0, false);
    w = __builtin_amdgcn_cvt_pk_fp8_f32(c, d, w, true);
    return (unsigned int)w;
}

// DPP add within a 16-lane row (VALU pipe; R10-proven)
template <int CTRL>
__device__ __forceinline__ float dppadd(float x) {
    int y = __builtin_amdgcn_update_dpp(0, __builtin_bit_cast(int, x),
                                        CTRL, 0xf, 0xf, true);
    return x + __builtin_bit_cast(float, y);
}
__device__ __forceinline__ float row16_sum(float x) {
    x = dppadd<0xB1>(x);    // quad_perm xor1
    x = dppadd<0x4E>(x);    // quad_perm xor2
    x = dppadd<0x124>(x);   // row_ror:4
    x = dppadd<0x128>(x);   // row_ror:8
    return x;
}

// decode triangular tile index (wave-uniform; verified R5-R14)
__device__ __forceinline__ void decode_tile(int idx, int nt, int& tm, int& tn) {
    float fnt = (float)nt;
    float disc = (2.0f * fnt + 1.0f) * (2.0f * fnt + 1.0f) - 8.0f * (float)idx;
    int t = (int)((2.0f * fnt + 1.0f - sqrtf(disc)) * 0.5f);
    if (t < 0) t = 0;
    if (t > nt - 1) t = nt - 1;
    while (t > 0 && idx < t * nt - t * (t - 1) / 2) --t;
    while (idx >= (t + 1) * nt - (t + 1) * t / 2) ++t;
    tm = t;
    tn = t + (idx - (t * nt - t * (t - 1) / 2));
}

// ---------------------------------------------------------------------------
// Kernel 1: fused prep (no memsets — everything exactly-once). 256 blocks x
// 32 rows (2 groups of 16). Per group: labels from coords/seg, normalize
// 4 rows/wave -> LDS, fragment-tiled fp8 writer (16 B/thread), class-sum
// accumulation Sloc[5][256]. End: slot writes Spart[bid][5][256],
// histpart[bid][8]; block 0 zeroes the finalize handshake (now 3 words:
// acc, done-counter, gram-arrival-counter).
// ---------------------------------------------------------------------------
__global__ __launch_bounds__(256) void
norm_kernel(const float* __restrict__ f,
            unsigned char* __restrict__ g2,
            const int* __restrict__ seg,
            const int* __restrict__ coords,
            const int* __restrict__ crw,
            const int* __restrict__ crh,
            const int* __restrict__ crd,
            int* __restrict__ lab,
            float* __restrict__ Spart,    // [256][5][256]
            int* __restrict__ histpart,   // [256][8]
            float* __restrict__ acc_done,
            int N, int H, int W, int D) {
    __shared__ float nrm[16][264];
    __shared__ float Sloc[5][256];
    __shared__ int lbl[16];
    __shared__ int histloc[8];

    const int tid = threadIdx.x;
    const int bid = blockIdx.x;
    const int lane = tid & 63;
    const int wave = tid >> 6;
    const int rbase = bid * 32;

    if (bid == 0 && tid == 0) {
        acc_done[0] = 0.0f;
        ((int*)acc_done)[1] = 0;   // out-writer handshake counter
        ((int*)acc_done)[2] = 0;   // gram arrival counter (grid sync)
    }
    if (tid < 8) histloc[tid] = 0;
#pragma unroll
    for (int c = 0; c < 5; ++c) Sloc[c][tid] = 0.0f;
    __syncthreads();

    for (int g = 0; g < 2; ++g) {
        const int grow0 = rbase + g * 16;
        if (tid < 16) {
            const int row = grow0 + tid;
            const int p = row & (N - 1);
            int c0 = coords[3 * p + 0];
            int c1 = coords[3 * p + 1];
            int c2 = coords[3 * p + 2];
            int i0 = (c0 * H) / crw[0];
            int i1 = (c1 * W) / crh[0];
            int i2 = (c2 * D) / crd[0];
            const int c = seg[(i0 * W + i1) * D + i2];
            lbl[tid] = c;
            if (row < N) {
                lab[row] = c;
                atomicAdd(&histloc[c], 1);
            }
        }
        const int rl = wave * 4;
#pragma unroll
        for (int q = 0; q < 4; ++q) {
            const int row = grow0 + rl + q;
            const float4 v = ((const float4*)(f + (size_t)row * C_DIM))[lane];
            float ss = v.x * v.x + v.y * v.y + v.z * v.z + v.w * v.w;
#pragma unroll
            for (int off = 32; off; off >>= 1) ss += __shfl_xor(ss, off, 64);
            const float inv = 1.0f / sqrtf(ss);
            *(float4*)&nrm[rl + q][lane * 4] =
                float4{v.x * inv, v.y * inv, v.z * inv, v.w * inv};
        }
        __syncthreads();

        // fragment-tiled fp8 writer: thread t -> blob bytes [16t, 16t+16)
        const int k0 = (tid >> 5) * 32 + ((tid >> 3) & 3) * 8;
        const float* ra = &nrm[(2 * tid) & 15][k0];
        const float* rb = &nrm[(2 * tid + 1) & 15][k0];
        uint4 o;
        o.x = pack4fp8(ra[0], ra[1], ra[2], ra[3]);
        o.y = pack4fp8(ra[4], ra[5], ra[6], ra[7]);
        o.z = pack4fp8(rb[0], rb[1], rb[2], rb[3]);
        o.w = pack4fp8(rb[4], rb[5], rb[6], rb[7]);
        *(uint4*)(g2 + (size_t)(bid * 2 + g) * 4096 + (size_t)tid * 16) = o;

        // class-sum accumulation: thread t owns dim t
#pragma unroll
        for (int rr = 0; rr < 16; ++rr)
            Sloc[lbl[rr]][tid] += nrm[rr][tid];
        __syncthreads();
    }

#pragma unroll
    for (int c = 0; c < 5; ++c)
        Spart[(size_t)bid * 1280 + c * 256 + tid] = Sloc[c][tid];
    if (tid < 8) histpart[bid * 8 + tid] = histloc[tid];
}

// ---------------------------------------------------------------------------
// Kernel 2: chunked-persistent symmetric Gram kernel + FUSED FINALIZE.
// Gram phase identical to R14 (prefetch-overlapped staging, se-only
// diag/off-diag epilogue). After the tile loop every block arrives at a
// device-scope counter (release). 512 blocks @ 2/CU (66.5 KB LDS, <=128
// VGPR via launch_bounds) are structurally co-resident, so a spin on the
// counter is deadlock-free. Blocks 0..255 then each finalize 32 rows
// (8 slot-loads/thread instead of the old 64-deep serial loop over 37
// blocks); blocks 256..260 do the per-class Spart reduction immediately
// (its inputs come from norm_kernel — ordered by the kernel boundary).
// Saves the third kernel launch + gap and shrinks the finalize tail ~4x.
// ---------------------------------------------------------------------------
__global__ __launch_bounds__(256, 2) void
gram_kernel(const unsigned char* __restrict__ G2,
            float* __restrict__ part,
            const float* __restrict__ Spart,
            const int* __restrict__ histpart,
            float* __restrict__ acc_done,
            float* __restrict__ out,
            int M, int N, int nt) {
    __shared__ unsigned char Abuf[32768];
    __shared__ unsigned char Bbuf[32768];
    __shared__ float red[2][2][128];

    const int tid = threadIdx.x;
    const int bid = blockIdx.x;
    const int lane = tid & 63;
    const int wave = tid >> 6;
    const int waveM = wave >> 1;
    const int waveN = wave & 1;
    const int cc = lane & 15;
    const int cq = lane >> 4;

    const int start = bid * 4 + (bid < 32 ? bid : 32);
    const int len = 4 + (bid < 32 ? 1 : 0);

    int tmCur, tnCur;
    decode_tile(start, nt, tmCur, tnCur);

    // prologue: stage first tile's panels
    {
        const unsigned char* gA = G2 + (size_t)tmCur * 32768;
#pragma unroll
        for (int i = 0; i < 8; ++i) {
            const int u = i * 256 + tid;
            __builtin_amdgcn_global_load_lds(
                (const __attribute__((address_space(1))) void*)(gA + (size_t)u * 16),
                (__attribute__((address_space(3))) void*)(&Abuf[(u & ~63) * 16]),
                16, 0, 0);
        }
        if (tnCur != tmCur) {
            const unsigned char* gB = G2 + (size_t)tnCur * 32768;
#pragma unroll
            for (int i = 0; i < 8; ++i) {
                const int u = i * 256 + tid;
                __builtin_amdgcn_global_load_lds(
                    (const __attribute__((address_space(1))) void*)(gB + (size_t)u * 16),
                    (__attribute__((address_space(3))) void*)(&Bbuf[(u & ~63) * 16]),
                    16, 0, 0);
            }
        }
    }

    for (int s = 0; s < len; ++s) {
        const int tm = tmCur, tn = tnCur;
        const int rowA0 = tm * 128;
        const int rowB0 = tn * 128;
        const bool diagTile = (tm == tn);
        const unsigned char* A = Abuf;
        const unsigned char* B = diagTile ? Abuf : Bbuf;

        __syncthreads();   // DMA complete (vmcnt drained) + red[] reads done

        floatx4 acc[4][4];
#pragma unroll
        for (int mi = 0; mi < 4; ++mi)
#pragma unroll
            for (int ni = 0; ni < 4; ++ni)
                acc[mi][ni] = floatx4{-1.0f, -1.0f, -1.0f, -1.0f};  // folds (sim-1)

#pragma unroll
        for (int ks = 0; ks < 8; ++ks) {  // K = 8 * 32 = 256
            long af[4], bf[4];
#pragma unroll
            for (int mi = 0; mi < 4; ++mi)
                af[mi] = *(const long*)&A[(size_t)((waveM * 4 + mi) * 8 + ks) * 512 + lane * 8];
#pragma unroll
            for (int ni = 0; ni < 4; ++ni)
                bf[ni] = *(const long*)&B[(size_t)((waveN * 4 + ni) * 8 + ks) * 512 + lane * 8];
#pragma unroll
            for (int mi = 0; mi < 4; ++mi)
#pragma unroll
                for (int ni = 0; ni < 4; ++ni)
                    acc[mi][ni] = __builtin_amdgcn_mfma_f32_16x16x32_fp8_fp8(
                        af[mi], bf[ni], acc[mi][ni], 0, 0, 0);
        }

        __syncthreads();   // all waves done reading A/B -> safe to overwrite

        // ---- prefetch next tile's panels (overlaps epilogue below) ----
        if (s + 1 < len) {
            int tmN, tnN;
            decode_tile(start + s + 1, nt, tmN, tnN);
            if (tmN != tm) {
                const unsigned char* gA = G2 + (size_t)tmN * 32768;
#pragma unroll
                for (int i = 0; i < 8; ++i) {
                    const int u = i * 256 + tid;
                    __builtin_amdgcn_global_load_lds(
                        (const __attribute__((address_space(1))) void*)(gA + (size_t)u * 16),
                        (__attribute__((address_space(3))) void*)(&Abuf[(u & ~63) * 16]),
                        16, 0, 0);
                }
            }
            if (tnN != tmN) {
                const unsigned char* gB = G2 + (size_t)tnN * 32768;
#pragma unroll
                for (int i = 0; i < 8; ++i) {
                    const int u = i * 256 + tid;
                    __builtin_amdgcn_global_load_lds(
                        (const __attribute__((address_space(1))) void*)(gB + (size_t)u * 16),
                        (__attribute__((address_space(3))) void*)(&Bbuf[(u & ~63) * 16]),
                        16, 0, 0);
                }
            }
            tmCur = tmN;
            tnCur = tnN;
        }

        // ---- se-only epilogue (acc regs + red[] only), diag-specialized ----
        if (!diagTile) {
            float bse[4] = {};
#pragma unroll
            for (int mi = 0; mi < 4; ++mi) {
#pragma unroll
                for (int r = 0; r < 4; ++r) {
                    const int lrow = waveM * 64 + mi * 16 + cq * 4 + r;
                    float se = 0.0f;
#pragma unroll
                    for (int ni = 0; ni < 4; ++ni) {
                        const float e = exp2f(acc[mi][ni][r] * K2_SCALE);
                        se += e;
                        bse[ni] += e;
                    }
                    se = row16_sum(se);
                    if (cc == 0) red[0][waveN][lrow] = se;
                }
            }
#pragma unroll
            for (int ni = 0; ni < 4; ++ni) {
                float se = bse[ni];
                se += __shfl_xor(se, 16, 64);
                se += __shfl_xor(se, 32, 64);
                if (cq == 0) red[1][waveM][waveN * 64 + ni * 16 + cc] = se;
            }
        } else {
#pragma unroll
            for (int mi = 0; mi < 4; ++mi) {
#pragma unroll
                for (int r = 0; r < 4; ++r) {
                    const int lrow = waveM * 64 + mi * 16 + cq * 4 + r;
                    const int grow = rowA0 + lrow;
                    float se = 0.0f;
#pragma unroll
                    for (int ni = 0; ni < 4; ++ni) {
                        const int gcol = rowB0 + waveN * 64 + ni * 16 + cc;
                        const float e = exp2f(acc[mi][ni][r] * K2_SCALE);
                        se += (gcol != grow) ? e : 0.0f;
                    }
                    se = row16_sum(se);
                    if (cc == 0) red[0][waveN][lrow] = se;
                }
            }
        }
        __syncthreads();   // red[] writes visible

        if (tid < 128)
            part[(size_t)tn * M + rowA0 + tid] = red[0][0][tid] + red[0][1][tid];
        if (!diagTile && tid >= 128)
            part[(size_t)tm * M + rowB0 + (tid - 128)] =
                red[1][0][tid - 128] + red[1][1][tid - 128];
        // no trailing barrier: the top-of-loop sync covers red[] reuse
    }

    // =========================== fused finalize ===========================
    __syncthreads();                       // all part stores of this block drained
    int* ctr = (int*)acc_done + 2;
    const int ntot = (int)gridDim.x;       // 512
    if (tid == 0) {
        __threadfence();                   // release: part visible device-wide
        __hip_atomic_fetch_add(ctr, 1, __ATOMIC_RELEASE, __HIP_MEMORY_SCOPE_AGENT);
    }

    const int rowblks = M >> 5;            // 256 blocks x 32 rows
    const int nblk = rowblks + 5;          // out-writer handshake count

    if (bid < rowblks) {
        // ---- per-row denominator: needs ALL blocks' part -> spin ----
        if (tid == 0) {
            while (__hip_atomic_load(ctr, __ATOMIC_RELAXED,
                                     __HIP_MEMORY_SCOPE_AGENT) < ntot)
                __builtin_amdgcn_s_sleep(2);
        }
        __syncthreads();
        __threadfence();                   // acquire: invalidate stale caches

        float* tr = (float*)Abuf;          // [8][32] scratch (gram done with Abuf)
        const int r_off = tid & 31;
        const int s_hi = tid >> 5;         // 0..7
        const int r0 = bid * 32;
        float se = 0.0f;
#pragma unroll
        for (int j = 0; j < 64; j += 8)
            se += part[(size_t)(s_hi + j) * (size_t)M + r0 + r_off];
        tr[tid] = se;
        __syncthreads();

        float bs = 0.0f;
        if (tid < 32) {
            float t = ((tr[tid] + tr[tid + 32]) + (tr[tid + 64] + tr[tid + 96])) +
                      ((tr[tid + 128] + tr[tid + 160]) + (tr[tid + 192] + tr[tid + 224]));
            float v = -logf(t);
#pragma unroll
            for (int off = 16; off; off >>= 1) v += __shfl_xor(v, off, 32);
            bs = v;
        }
        if (tid == 0) {
            atomicAdd(&acc_done[0], bs);
            __threadfence();
            int old = atomicAdd((int*)acc_done + 1, 1);
            if (old == nblk - 1)
                out[0] = -atomicAdd(&acc_done[0], 0.0f) / (float)M;
        }
    } else if (bid < rowblks + 5) {
        // ---- per-class |S_c|^2 term: inputs from norm_kernel, no spin ----
        const int c = bid - rowblks;
        float* sred = (float*)Abuf;
        int* hred = (int*)(Abuf + 4096);
        float a0 = 0.0f, a1 = 0.0f, a2 = 0.0f, a3 = 0.0f;
        float a4 = 0.0f, a5 = 0.0f, a6 = 0.0f, a7 = 0.0f;
        const float* Sp = Spart + c * 256 + tid;
        for (int b = 0; b < 256; b += 8) {
            a0 += Sp[(size_t)(b + 0) * 1280];
            a1 += Sp[(size_t)(b + 1) * 1280];
            a2 += Sp[(size_t)(b + 2) * 1280];
            a3 += Sp[(size_t)(b + 3) * 1280];
            a4 += Sp[(size_t)(b + 4) * 1280];
            a5 += Sp[(size_t)(b + 5) * 1280];
            a6 += Sp[(size_t)(b + 6) * 1280];
            a7 += Sp[(size_t)(b + 7) * 1280];
        }
        const float v = ((a0 + a1) + (a2 + a3)) + ((a4 + a5) + (a6 + a7));
        sred[tid] = v * v;
        hred[tid] = histpart[tid * 8 + c];
        __syncthreads();
        for (int k = 128; k; k >>= 1) {
            if (tid < k) {
                sred[tid] += sred[tid + k];
                hred[tid] += hred[tid + k];
            }
            __syncthreads();
        }
        if (tid == 0) {
            const int ntps = M / N;
            const float S2 = sred[0];
            const float Mc = (float)(ntps * hred[0]);
            const float cnt = Mc - 1.0f;
            float contrib = (cnt > 0.0f) ? INV_T * (S2 - Mc) / cnt : 0.0f;
            if (c == 0) contrib -= INV_T * (float)M;
            atomicAdd(&acc_done[0], contrib);
            __threadfence();
            int old = atomicAdd((int*)acc_done + 1, 1);
            if (old == nblk - 1)
                out[0] = -atomicAdd(&acc_done[0], 0.0f) / (float)M;
        }
    }
    // bid >= rowblks+5: arrival done, exit (frees CUs immediately)
}

extern "C" void kernel_launch(void* const* d_in, const int* in_sizes, int n_in,
                              void* d_out, int out_size, void* d_ws, size_t ws_size,
                              hipStream_t stream) {
    const float* features = (const float*)d_in[0];
    const int* labels_seg = (const int*)d_in[1];
    const int* labels_coords = (const int*)d_in[2];
    const int* crw = (const int*)d_in[3];
    const int* crh = (const int*)d_in[4];
    const int* crd = (const int*)d_in[5];
    float* out = (float*)d_out;

    const int N = in_sizes[2] / 3;          // 4096 patches
    const int M = in_sizes[0] / C_DIM;      // 8192 rows
    const int H = 128, W = 128, D = 128;
    const int nt = M / 128;                 // 64 row-blocks

    // workspace layout (no memsets — all exactly-once writes)
    char* ws = (char*)d_ws;
    unsigned char* g2 = (unsigned char*)ws;                  // 2 MB fp8 tiled
    char* p1 = ws + (size_t)M * C_DIM;
    int* lab = (int*)p1;                                     // N ints
    char* p2 = p1 + (size_t)N * 4;
    float* part = (float*)p2;                                // nt*M f32 (2 MB)
    char* p3 = p2 + (size_t)nt * M * 4;
    float* Spart = (float*)p3;                               // 256*5*256 f32 (1.25 MB)
    char* p4 = p3 + (size_t)256 * 1280 * 4;
    int* histpart = (int*)p4;                                // 256*8 ints
    float* acc_done = (float*)(p4 + 256 * 8 * 4);            // {acc, done, arrive}

    norm_kernel<<<M / 32, 256, 0, stream>>>(features, g2, labels_seg,
                                            labels_coords, crw, crh, crd, lab,
                                            Spart, histpart, acc_done,
                                            N, H, W, D);

    gram_kernel<<<512, 256, 0, stream>>>(g2, part, Spart, histpart,
                                         acc_done, out, M, N, nt);
}

// Round 2
// 123.088 us; speedup vs baseline: 1.3667x; 1.3667x over previous
//
#include <hip/hip_runtime.h>
#include <hip/hip_bf16.h>

typedef __attribute__((ext_vector_type(4))) float floatx4;

#define C_DIM 256
#define INV_T 14.285714285714286f
// (1/T) * log2(e) : logits scaled to base-2 so exp2f -> v_exp_f32 directly.
#define K2_SCALE 20.60992915f

// pack 4 fp32 -> 4 OCP fp8 e4m3 bytes in one dword (ascending order)
__device__ __forceinline__ unsigned int pack4fp8(float a, float b, float c, float d) {
    int w = __builtin_amdgcn_cvt_pk_fp8_f32(a, b, 0, false);
    w = __builtin_amdgcn_cvt_pk_fp8_f32(c, d, w, true);
    return (unsigned int)w;
}

// DPP add within a 16-lane row (VALU pipe; R10-proven)
template <int CTRL>
__device__ __forceinline__ float dppadd(float x) {
    int y = __builtin_amdgcn_update_dpp(0, __builtin_bit_cast(int, x),
                                        CTRL, 0xf, 0xf, true);
    return x + __builtin_bit_cast(float, y);
}
__device__ __forceinline__ float row16_sum(float x) {
    x = dppadd<0xB1>(x);    // quad_perm xor1
    x = dppadd<0x4E>(x);    // quad_perm xor2
    x = dppadd<0x124>(x);   // row_ror:4
    x = dppadd<0x128>(x);   // row_ror:8
    return x;
}

// decode triangular tile index (wave-uniform; verified R5-R14)
__device__ __forceinline__ void decode_tile(int idx, int nt, int& tm, int& tn) {
    float fnt = (float)nt;
    float disc = (2.0f * fnt + 1.0f) * (2.0f * fnt + 1.0f) - 8.0f * (float)idx;
    int t = (int)((2.0f * fnt + 1.0f - sqrtf(disc)) * 0.5f);
    if (t < 0) t = 0;
    if (t > nt - 1) t = nt - 1;
    while (t > 0 && idx < t * nt - t * (t - 1) / 2) --t;
    while (idx >= (t + 1) * nt - (t + 1) * t / 2) ++t;
    tm = t;
    tn = t + (idx - (t * nt - t * (t - 1) / 2));
}

// ---------------------------------------------------------------------------
// Kernel 1: fused prep (no memsets — everything exactly-once). 256 blocks x
// 32 rows (2 groups of 16). Per group: labels from coords/seg, normalize
// 4 rows/wave -> LDS, fragment-tiled fp8 writer (16 B/thread), class-sum
// accumulation Sloc[5][256]. End: slot writes Spart[bid][5][256],
// histpart[bid][8]; block 0 zeroes the finalize handshake. (R0-verbatim)
// ---------------------------------------------------------------------------
__global__ __launch_bounds__(256) void
norm_kernel(const float* __restrict__ f,
            unsigned char* __restrict__ g2,
            const int* __restrict__ seg,
            const int* __restrict__ coords,
            const int* __restrict__ crw,
            const int* __restrict__ crh,
            const int* __restrict__ crd,
            int* __restrict__ lab,
            float* __restrict__ Spart,    // [256][5][256]
            int* __restrict__ histpart,   // [256][8]
            float* __restrict__ acc_done,
            int N, int H, int W, int D) {
    __shared__ float nrm[16][264];
    __shared__ float Sloc[5][256];
    __shared__ int lbl[16];
    __shared__ int histloc[8];

    const int tid = threadIdx.x;
    const int bid = blockIdx.x;
    const int lane = tid & 63;
    const int wave = tid >> 6;
    const int rbase = bid * 32;

    if (bid == 0 && tid == 0) {
        acc_done[0] = 0.0f;
        ((int*)acc_done)[1] = 0;
    }
    if (tid < 8) histloc[tid] = 0;
#pragma unroll
    for (int c = 0; c < 5; ++c) Sloc[c][tid] = 0.0f;
    __syncthreads();

    for (int g = 0; g < 2; ++g) {
        const int grow0 = rbase + g * 16;
        if (tid < 16) {
            const int row = grow0 + tid;
            const int p = row & (N - 1);
            int c0 = coords[3 * p + 0];
            int c1 = coords[3 * p + 1];
            int c2 = coords[3 * p + 2];
            int i0 = (c0 * H) / crw[0];
            int i1 = (c1 * W) / crh[0];
            int i2 = (c2 * D) / crd[0];
            const int c = seg[(i0 * W + i1) * D + i2];
            lbl[tid] = c;
            if (row < N) {
                lab[row] = c;
                atomicAdd(&histloc[c], 1);
            }
        }
        const int rl = wave * 4;
#pragma unroll
        for (int q = 0; q < 4; ++q) {
            const int row = grow0 + rl + q;
            const float4 v = ((const float4*)(f + (size_t)row * C_DIM))[lane];
            float ss = v.x * v.x + v.y * v.y + v.z * v.z + v.w * v.w;
#pragma unroll
            for (int off = 32; off; off >>= 1) ss += __shfl_xor(ss, off, 64);
            const float inv = 1.0f / sqrtf(ss);
            *(float4*)&nrm[rl + q][lane * 4] =
                float4{v.x * inv, v.y * inv, v.z * inv, v.w * inv};
        }
        __syncthreads();

        // fragment-tiled fp8 writer: thread t -> blob bytes [16t, 16t+16)
        const int k0 = (tid >> 5) * 32 + ((tid >> 3) & 3) * 8;
        const float* ra = &nrm[(2 * tid) & 15][k0];
        const float* rb = &nrm[(2 * tid + 1) & 15][k0];
        uint4 o;
        o.x = pack4fp8(ra[0], ra[1], ra[2], ra[3]);
        o.y = pack4fp8(ra[4], ra[5], ra[6], ra[7]);
        o.z = pack4fp8(rb[0], rb[1], rb[2], rb[3]);
        o.w = pack4fp8(rb[4], rb[5], rb[6], rb[7]);
        *(uint4*)(g2 + (size_t)(bid * 2 + g) * 4096 + (size_t)tid * 16) = o;

        // class-sum accumulation: thread t owns dim t
#pragma unroll
        for (int rr = 0; rr < 16; ++rr)
            Sloc[lbl[rr]][tid] += nrm[rr][tid];
        __syncthreads();
    }

#pragma unroll
    for (int c = 0; c < 5; ++c)
        Spart[(size_t)bid * 1280 + c * 256 + tid] = Sloc[c][tid];
    if (tid < 8) histpart[bid * 8 + tid] = histloc[tid];
}

// ---------------------------------------------------------------------------
// Kernel 2: chunked-persistent symmetric Gram kernel, PREFETCH-OVERLAPPED
// staging (R0-verbatim — no fused finalize; the R1 experiment showed the
// arrival/acquire fences cost ~90 us in L2 writeback/invalidate traffic).
// ---------------------------------------------------------------------------
__global__ __launch_bounds__(256, 2) void
gram_kernel(const unsigned char* __restrict__ G2,
            float* __restrict__ part,
            int M, int nt) {
    __shared__ unsigned char Abuf[32768];
    __shared__ unsigned char Bbuf[32768];
    __shared__ float red[2][2][128];

    const int tid = threadIdx.x;
    const int bid = blockIdx.x;
    const int lane = tid & 63;
    const int wave = tid >> 6;
    const int waveM = wave >> 1;
    const int waveN = wave & 1;
    const int cc = lane & 15;
    const int cq = lane >> 4;

    const int start = bid * 4 + (bid < 32 ? bid : 32);
    const int len = 4 + (bid < 32 ? 1 : 0);

    int tmCur, tnCur;
    decode_tile(start, nt, tmCur, tnCur);

    // prologue: stage first tile's panels
    {
        const unsigned char* gA = G2 + (size_t)tmCur * 32768;
#pragma unroll
        for (int i = 0; i < 8; ++i) {
            const int u = i * 256 + tid;
            __builtin_amdgcn_global_load_lds(
                (const __attribute__((address_space(1))) void*)(gA + (size_t)u * 16),
                (__attribute__((address_space(3))) void*)(&Abuf[(u & ~63) * 16]),
                16, 0, 0);
        }
        if (tnCur != tmCur) {
            const unsigned char* gB = G2 + (size_t)tnCur * 32768;
#pragma unroll
            for (int i = 0; i < 8; ++i) {
                const int u = i * 256 + tid;
                __builtin_amdgcn_global_load_lds(
                    (const __attribute__((address_space(1))) void*)(gB + (size_t)u * 16),
                    (__attribute__((address_space(3))) void*)(&Bbuf[(u & ~63) * 16]),
                    16, 0, 0);
            }
        }
    }

    for (int s = 0; s < len; ++s) {
        const int tm = tmCur, tn = tnCur;
        const int rowA0 = tm * 128;
        const int rowB0 = tn * 128;
        const bool diagTile = (tm == tn);
        const unsigned char* A = Abuf;
        const unsigned char* B = diagTile ? Abuf : Bbuf;

        __syncthreads();   // DMA complete (vmcnt drained) + red[] reads done

        floatx4 acc[4][4];
#pragma unroll
        for (int mi = 0; mi < 4; ++mi)
#pragma unroll
            for (int ni = 0; ni < 4; ++ni)
                acc[mi][ni] = floatx4{-1.0f, -1.0f, -1.0f, -1.0f};  // folds (sim-1)

#pragma unroll
        for (int ks = 0; ks < 8; ++ks) {  // K = 8 * 32 = 256
            long af[4], bf[4];
#pragma unroll
            for (int mi = 0; mi < 4; ++mi)
                af[mi] = *(const long*)&A[(size_t)((waveM * 4 + mi) * 8 + ks) * 512 + lane * 8];
#pragma unroll
            for (int ni = 0; ni < 4; ++ni)
                bf[ni] = *(const long*)&B[(size_t)((waveN * 4 + ni) * 8 + ks) * 512 + lane * 8];
#pragma unroll
            for (int mi = 0; mi < 4; ++mi)
#pragma unroll
                for (int ni = 0; ni < 4; ++ni)
                    acc[mi][ni] = __builtin_amdgcn_mfma_f32_16x16x32_fp8_fp8(
                        af[mi], bf[ni], acc[mi][ni], 0, 0, 0);
        }

        __syncthreads();   // all waves done reading A/B -> safe to overwrite

        // ---- prefetch next tile's panels (overlaps epilogue below) ----
        if (s + 1 < len) {
            int tmN, tnN;
            decode_tile(start + s + 1, nt, tmN, tnN);
            if (tmN != tm) {
                const unsigned char* gA = G2 + (size_t)tmN * 32768;
#pragma unroll
                for (int i = 0; i < 8; ++i) {
                    const int u = i * 256 + tid;
                    __builtin_amdgcn_global_load_lds(
                        (const __attribute__((address_space(1))) void*)(gA + (size_t)u * 16),
                        (__attribute__((address_space(3))) void*)(&Abuf[(u & ~63) * 16]),
                        16, 0, 0);
                }
            }
            if (tnN != tmN) {
                const unsigned char* gB = G2 + (size_t)tnN * 32768;
#pragma unroll
                for (int i = 0; i < 8; ++i) {
                    const int u = i * 256 + tid;
                    __builtin_amdgcn_global_load_lds(
                        (const __attribute__((address_space(1))) void*)(gB + (size_t)u * 16),
                        (__attribute__((address_space(3))) void*)(&Bbuf[(u & ~63) * 16]),
                        16, 0, 0);
                }
            }
            tmCur = tmN;
            tnCur = tnN;
        }

        // ---- se-only epilogue (acc regs + red[] only), diag-specialized ----
        if (!diagTile) {
            float bse[4] = {};
#pragma unroll
            for (int mi = 0; mi < 4; ++mi) {
#pragma unroll
                for (int r = 0; r < 4; ++r) {
                    const int lrow = waveM * 64 + mi * 16 + cq * 4 + r;
                    float se = 0.0f;
#pragma unroll
                    for (int ni = 0; ni < 4; ++ni) {
                        const float e = exp2f(acc[mi][ni][r] * K2_SCALE);
                        se += e;
                        bse[ni] += e;
                    }
                    se = row16_sum(se);
                    if (cc == 0) red[0][waveN][lrow] = se;
                }
            }
#pragma unroll
            for (int ni = 0; ni < 4; ++ni) {
                float se = bse[ni];
                se += __shfl_xor(se, 16, 64);
                se += __shfl_xor(se, 32, 64);
                if (cq == 0) red[1][waveM][waveN * 64 + ni * 16 + cc] = se;
            }
        } else {
#pragma unroll
            for (int mi = 0; mi < 4; ++mi) {
#pragma unroll
                for (int r = 0; r < 4; ++r) {
                    const int lrow = waveM * 64 + mi * 16 + cq * 4 + r;
                    const int grow = rowA0 + lrow;
                    float se = 0.0f;
#pragma unroll
                    for (int ni = 0; ni < 4; ++ni) {
                        const int gcol = rowB0 + waveN * 64 + ni * 16 + cc;
                        const float e = exp2f(acc[mi][ni][r] * K2_SCALE);
                        se += (gcol != grow) ? e : 0.0f;
                    }
                    se = row16_sum(se);
                    if (cc == 0) red[0][waveN][lrow] = se;
                }
            }
        }
        __syncthreads();   // red[] writes visible

        if (tid < 128)
            part[(size_t)tn * M + rowA0 + tid] = red[0][0][tid] + red[0][1][tid];
        if (!diagTile && tid >= 128)
            part[(size_t)tm * M + rowB0 + (tid - 128)] =
                red[1][0][tid - 128] + red[1][1][tid - 128];
        // no trailing barrier: the top-of-loop sync covers red[] reuse
    }
}

// ---------------------------------------------------------------------------
// Kernel 3: finalize, REPARALLELIZED row phase (the one structural win from
// the R1 experiment, without the fused grid-sync):
//   Blocks 0..255: 32 rows each. Thread (s_hi=tid>>5, r=tid&31) sums 8 of
//   the 64 part-slots for its row -> LDS [8][32] transpose -> 32 lanes do
//   the final 8-way add + -logf + shuffle-reduce. 8 independent loads per
//   thread instead of the old 64-deep serial loop over only 32 blocks.
//   Blocks 256..260: one class each (R0-verbatim |S_c|^2 sweep).
//   acc/done handshake over 261 blocks; last block writes the loss.
// ---------------------------------------------------------------------------
__global__ __launch_bounds__(256) void
finalize_kernel(const float* __restrict__ part,
                const float* __restrict__ Spart,
                const int* __restrict__ histpart,
                float* __restrict__ acc_done,
                float* __restrict__ out,
                int M, int N, int nslots, int rowblks) {
    __shared__ float sred[256];
    __shared__ int hred[256];

    const int tid = threadIdx.x;
    const int bid = blockIdx.x;
    const int nblk = rowblks + 5;

    if (bid < rowblks) {
        // ---- per-row denominator: 32 rows, 8 slot-loads per thread ----
        const int r_off = tid & 31;
        const int s_hi = tid >> 5;         // 0..7
        const int r0 = bid * 32;
        float se = 0.0f;
#pragma unroll
        for (int j = 0; j < 64; j += 8)
            se += part[(size_t)(s_hi + j) * (size_t)M + r0 + r_off];
        sred[tid] = se;
        __syncthreads();

        float bs = 0.0f;
        if (tid < 32) {
            float t = ((sred[tid] + sred[tid + 32]) + (sred[tid + 64] + sred[tid + 96])) +
                      ((sred[tid + 128] + sred[tid + 160]) + (sred[tid + 192] + sred[tid + 224]));
            float v = -logf(t);
#pragma unroll
            for (int off = 16; off; off >>= 1) v += __shfl_xor(v, off, 32);
            bs = v;
        }
        if (tid == 0) {
            atomicAdd(&acc_done[0], bs);
            __threadfence();
            int old = atomicAdd((int*)acc_done + 1, 1);
            if (old == nblk - 1)
                out[0] = -atomicAdd(&acc_done[0], 0.0f) / (float)M;  // atomic read
        }
    } else {
        // ---- per-class |S_c|^2 term (R0-verbatim) ----
        const int c = bid - rowblks;
        float a0 = 0.0f, a1 = 0.0f, a2 = 0.0f, a3 = 0.0f;
        float a4 = 0.0f, a5 = 0.0f, a6 = 0.0f, a7 = 0.0f;
        const float* Sp = Spart + c * 256 + tid;
        for (int b = 0; b < 256; b += 8) {
            a0 += Sp[(size_t)(b + 0) * 1280];
            a1 += Sp[(size_t)(b + 1) * 1280];
            a2 += Sp[(size_t)(b + 2) * 1280];
            a3 += Sp[(size_t)(b + 3) * 1280];
            a4 += Sp[(size_t)(b + 4) * 1280];
            a5 += Sp[(size_t)(b + 5) * 1280];
            a6 += Sp[(size_t)(b + 6) * 1280];
            a7 += Sp[(size_t)(b + 7) * 1280];
        }
        const float v = ((a0 + a1) + (a2 + a3)) + ((a4 + a5) + (a6 + a7));
        sred[tid] = v * v;
        hred[tid] = histpart[tid * 8 + c];
        __syncthreads();
        for (int k = 128; k; k >>= 1) {
            if (tid < k) {
                sred[tid] += sred[tid + k];
                hred[tid] += hred[tid + k];
            }
            __syncthreads();
        }
        if (tid == 0) {
            const int ntps = M / N;
            const float S2 = sred[0];
            const float Mc = (float)(ntps * hred[0]);
            const float cnt = Mc - 1.0f;
            float contrib = (cnt > 0.0f) ? INV_T * (S2 - Mc) / cnt : 0.0f;
            if (c == 0) contrib -= INV_T * (float)M;
            atomicAdd(&acc_done[0], contrib);
            __threadfence();
            int old = atomicAdd((int*)acc_done + 1, 1);
            if (old == nblk - 1)
                out[0] = -atomicAdd(&acc_done[0], 0.0f) / (float)M;  // atomic read
        }
    }
}

extern "C" void kernel_launch(void* const* d_in, const int* in_sizes, int n_in,
                              void* d_out, int out_size, void* d_ws, size_t ws_size,
                              hipStream_t stream) {
    const float* features = (const float*)d_in[0];
    const int* labels_seg = (const int*)d_in[1];
    const int* labels_coords = (const int*)d_in[2];
    const int* crw = (const int*)d_in[3];
    const int* crh = (const int*)d_in[4];
    const int* crd = (const int*)d_in[5];
    float* out = (float*)d_out;

    const int N = in_sizes[2] / 3;          // 4096 patches
    const int M = in_sizes[0] / C_DIM;      // 8192 rows
    const int H = 128, W = 128, D = 128;
    const int nt = M / 128;                 // 64 row-blocks

    // workspace layout (no memsets — all exactly-once writes)
    char* ws = (char*)d_ws;
    unsigned char* g2 = (unsigned char*)ws;                  // 2 MB fp8 tiled
    char* p1 = ws + (size_t)M * C_DIM;
    int* lab = (int*)p1;                                     // N ints
    char* p2 = p1 + (size_t)N * 4;
    float* part = (float*)p2;                                // nt*M f32 (2 MB)
    char* p3 = p2 + (size_t)nt * M * 4;
    float* Spart = (float*)p3;                               // 256*5*256 f32 (1.25 MB)
    char* p4 = p3 + (size_t)256 * 1280 * 4;
    int* histpart = (int*)p4;                                // 256*8 ints
    float* acc_done = (float*)(p4 + 256 * 8 * 4);            // {acc, done}

    norm_kernel<<<M / 32, 256, 0, stream>>>(features, g2, labels_seg,
                                            labels_coords, crw, crh, crd, lab,
                                            Spart, histpart, acc_done,
                                            N, H, W, D);

    gram_kernel<<<512, 256, 0, stream>>>(g2, part, M, nt);

    const int rowblks = M / 32;             // 256
    finalize_kernel<<<rowblks + 5, 256, 0, stream>>>(part, Spart, histpart,
                                                     acc_done, out, M, N, nt,
                                                     rowblks);
}